// Round 5
// baseline (164.728 us; speedup 1.0000x reference)
//
#include <hip/hip_runtime.h>

#define IN_C 128
#define OUT_C 256
#define LN_EPS 1e-5f
#define SCAN_BLK 1024

typedef __attribute__((ext_vector_type(8))) short bf16x8;
typedef __attribute__((ext_vector_type(4))) float f32x4;

__device__ __forceinline__ unsigned int f2bf(float f) {
    unsigned int u = __float_as_uint(f);
    return (u + 0x7fffu + ((u >> 16) & 1u)) >> 16;   // RNE
}
__device__ __forceinline__ float bf_lo(unsigned int p) { return __uint_as_float(p << 16); }
__device__ __forceinline__ float bf_hi(unsigned int p) { return __uint_as_float(p & 0xffff0000u); }

// ---------- pass 1: per-edge slot reservation (the ONLY atomic pass) ----------
__global__ __launch_bounds__(256) void k_slot(const int* __restrict__ col,
                                              int* __restrict__ cursor,
                                              unsigned short* __restrict__ slot, int E) {
    int i = blockIdx.x * 256 + threadIdx.x;
    int base = i * 2;
    if (base + 1 < E) {
        int2 c = *reinterpret_cast<const int2*>(col + base);
        unsigned short s0 = (unsigned short)atomicAdd(&cursor[c.x], 1);
        unsigned short s1 = (unsigned short)atomicAdd(&cursor[c.y], 1);
        ushort2 sv; sv.x = s0; sv.y = s1;
        *reinterpret_cast<ushort2*>(slot + base) = sv;
    } else if (base < E) {
        slot[base] = (unsigned short)atomicAdd(&cursor[col[base]], 1);
    }
}

// ---------- scan of deg (=cursor) -> exclusive ptr, plus dinv = rsqrt(deg+1) ----------
__global__ __launch_bounds__(1024) void k_scan1(const int* __restrict__ deg, int* __restrict__ ptr,
                                                int* __restrict__ bsum, float* __restrict__ dinv, int n) {
    __shared__ int s[SCAN_BLK];
    int t = threadIdx.x;
    int i = blockIdx.x * SCAN_BLK + t;
    int v = (i < n) ? deg[i] : 0;
    s[t] = v;
    __syncthreads();
    for (int off = 1; off < SCAN_BLK; off <<= 1) {
        int add = (t >= off) ? s[t - off] : 0;
        __syncthreads();
        s[t] += add;
        __syncthreads();
    }
    if (i < n) { ptr[i] = s[t] - v; dinv[i] = rsqrtf((float)(v + 1)); }
    if (t == SCAN_BLK - 1) bsum[blockIdx.x] = s[t];
}

__global__ __launch_bounds__(64) void k_scan2(int* __restrict__ bsum, int nb) {
    __shared__ int s[64];
    int t = threadIdx.x;
    int v = (t < nb) ? bsum[t] : 0;
    s[t] = v;
    __syncthreads();
    for (int off = 1; off < 64; off <<= 1) {
        int add = (t >= off) ? s[t - off] : 0;
        __syncthreads();
        s[t] += add;
        __syncthreads();
    }
    if (t < nb) bsum[t] = s[t] - v;
}

__global__ __launch_bounds__(256) void k_scan3(int* __restrict__ ptr, const int* __restrict__ bsum,
                                               int n, int E) {
    int i = blockIdx.x * 256 + threadIdx.x;
    if (i < n) ptr[i] += bsum[i / SCAN_BLK];
    if (i == 0) ptr[n] = E;
}

// ---------- pass 2: atomic-free CSR placement ----------
__global__ __launch_bounds__(256) void k_place(const int* __restrict__ row, const int* __restrict__ col,
                                               const int* __restrict__ ptr,
                                               const unsigned short* __restrict__ slot,
                                               int* __restrict__ csr_row, int E) {
    int i = blockIdx.x * 256 + threadIdx.x;
    int base = i * 2;
    if (base + 1 < E) {
        int2 r = *reinterpret_cast<const int2*>(row + base);
        int2 c = *reinterpret_cast<const int2*>(col + base);
        ushort2 s = *reinterpret_cast<const ushort2*>(slot + base);
        csr_row[ptr[c.x] + s.x] = r.x;
        csr_row[ptr[c.y] + s.y] = r.y;
    } else if (base < E) {
        csr_row[ptr[col[base]] + slot[base]] = row[base];
    }
}

// ---------- conversions: x->bf16 (plain and dinv-scaled), weights->fragment order ----------
__global__ __launch_bounds__(256) void k_convert(const float* __restrict__ x,
                                                 const float* __restrict__ dinv,
                                                 const float* __restrict__ Wg,
                                                 const float* __restrict__ Wr,
                                                 unsigned short* __restrict__ x_bf,
                                                 unsigned short* __restrict__ xs_bf,
                                                 unsigned short* __restrict__ wgf,
                                                 unsigned short* __restrict__ wrf,
                                                 int n) {
    int gid = blockIdx.x * 256 + threadIdx.x;
    int nx8 = n * (IN_C / 8);
    if (gid < nx8) {
        float dn = dinv[gid >> 4];
        const float4* xv = reinterpret_cast<const float4*>(x) + (size_t)gid * 2;
        float4 a = xv[0], b = xv[1];
        uint4 o, os;
        o.x  = f2bf(a.x) | (f2bf(a.y) << 16);
        o.y  = f2bf(a.z) | (f2bf(a.w) << 16);
        o.z  = f2bf(b.x) | (f2bf(b.y) << 16);
        o.w  = f2bf(b.z) | (f2bf(b.w) << 16);
        os.x = f2bf(a.x * dn) | (f2bf(a.y * dn) << 16);
        os.y = f2bf(a.z * dn) | (f2bf(a.w * dn) << 16);
        os.z = f2bf(b.x * dn) | (f2bf(b.y * dn) << 16);
        os.w = f2bf(b.z * dn) | (f2bf(b.w * dn) << 16);
        reinterpret_cast<uint4*>(x_bf)[gid]  = o;
        reinterpret_cast<uint4*>(xs_bf)[gid] = os;
    }
    if (gid < 8192) {  // weight fragments
        int wsel = gid >> 12;
        int u = gid & 4095;
        int ct = u >> 8, kt = (u >> 6) & 3, l = u & 63;
        int k0 = kt * 32 + (l >> 4) * 8;
        int colw = ct * 16 + (l & 15);
        const float* W = wsel ? Wr : Wg;
        unsigned short* Wf = wsel ? wrf : wgf;
        uint4 o;
        unsigned int s[8];
#pragma unroll
        for (int e = 0; e < 8; ++e) s[e] = f2bf(W[(size_t)(k0 + e) * OUT_C + colw]);
        o.x = s[0] | (s[1] << 16); o.y = s[2] | (s[3] << 16);
        o.z = s[4] | (s[5] << 16); o.w = s[6] | (s[7] << 16);
        reinterpret_cast<uint4*>(Wf)[u] = o;
    }
}

// ---------- aggregation: agg[c] = dinv[c] * (xs[c] + sum_e xs[r]), unroll x8 ----------
__global__ __launch_bounds__(256) void k_agg(const unsigned int* __restrict__ xs32,
                                             const float* __restrict__ dinv,
                                             const int* __restrict__ ptr,
                                             const int* __restrict__ csr_row,
                                             unsigned short* __restrict__ agg_bf, int n) {
    int c = blockIdx.x * 4 + (threadIdx.x >> 6);
    if (c >= n) return;
    int lane = threadIdx.x & 63;
    float dc = dinv[c];
    unsigned int p = xs32[(size_t)c * 64 + lane];
    float a0 = bf_lo(p), a1 = bf_hi(p);
    int e = ptr[c], end = ptr[c + 1];
    for (; e + 8 <= end; e += 8) {
        int r0 = csr_row[e],     r1 = csr_row[e + 1], r2 = csr_row[e + 2], r3 = csr_row[e + 3];
        int r4 = csr_row[e + 4], r5 = csr_row[e + 5], r6 = csr_row[e + 6], r7 = csr_row[e + 7];
        unsigned int q0 = xs32[(size_t)r0 * 64 + lane];
        unsigned int q1 = xs32[(size_t)r1 * 64 + lane];
        unsigned int q2 = xs32[(size_t)r2 * 64 + lane];
        unsigned int q3 = xs32[(size_t)r3 * 64 + lane];
        unsigned int q4 = xs32[(size_t)r4 * 64 + lane];
        unsigned int q5 = xs32[(size_t)r5 * 64 + lane];
        unsigned int q6 = xs32[(size_t)r6 * 64 + lane];
        unsigned int q7 = xs32[(size_t)r7 * 64 + lane];
        a0 += bf_lo(q0); a1 += bf_hi(q0);
        a0 += bf_lo(q1); a1 += bf_hi(q1);
        a0 += bf_lo(q2); a1 += bf_hi(q2);
        a0 += bf_lo(q3); a1 += bf_hi(q3);
        a0 += bf_lo(q4); a1 += bf_hi(q4);
        a0 += bf_lo(q5); a1 += bf_hi(q5);
        a0 += bf_lo(q6); a1 += bf_hi(q6);
        a0 += bf_lo(q7); a1 += bf_hi(q7);
    }
    for (; e < end; ++e) {
        unsigned int q = xs32[(size_t)csr_row[e] * 64 + lane];
        a0 += bf_lo(q); a1 += bf_hi(q);
    }
    a0 *= dc; a1 *= dc;
    *reinterpret_cast<unsigned int*>(agg_bf + (size_t)c * IN_C + lane * 2) = f2bf(a0) | (f2bf(a1) << 16);
}

// ---------- fused MFMA dual-GEMM + LN + ReLU + residual; register-resident B ----------
// 8 waves/block; wave w owns cols [w*32, w*32+32). B loaded once, grid-stride over 32-row tiles.
__global__ __launch_bounds__(512, 2) void k_mfma(const unsigned short* __restrict__ agg_bf,
                                                 const unsigned short* __restrict__ x_bf,
                                                 const unsigned short* __restrict__ wgf,
                                                 const unsigned short* __restrict__ wrf,
                                                 const float* __restrict__ bgc,
                                                 const float* __restrict__ gamma,
                                                 const float* __restrict__ beta,
                                                 const float* __restrict__ brc,
                                                 float* __restrict__ out, int n, int ntiles) {
    int tid = threadIdx.x;
    int w = tid >> 6, l = tid & 63;
    int g = l >> 4;        // row-group within 16x16 C tile / k-slice selector for A
    int lc = l & 15;       // col-within-16 (and A-row selector)

    // ---- B fragments, loaded ONCE: [ct2][kt] for each weight matrix ----
    bf16x8 Bg[2][4], Br[2][4];
#pragma unroll
    for (int ct2 = 0; ct2 < 2; ++ct2) {
        int ctg = w * 2 + ct2;
#pragma unroll
        for (int kt = 0; kt < 4; ++kt) {
            size_t idx = ((size_t)(ctg * 4 + kt) * 64 + l) * 8;
            Bg[ct2][kt] = *reinterpret_cast<const bf16x8*>(wgf + idx);
            Br[ct2][kt] = *reinterpret_cast<const bf16x8*>(wrf + idx);
        }
    }
    // per-lane epilogue constants (col-fixed)
    float bgj[2], gj[2], bj[2], brj[2];
    int colj[2];
#pragma unroll
    for (int ct2 = 0; ct2 < 2; ++ct2) {
        int c = (w * 2 + ct2) * 16 + lc;
        colj[ct2] = c;
        bgj[ct2] = bgc[c]; gj[ct2] = gamma[c]; bj[ct2] = beta[c]; brj[ct2] = brc[c];
    }

    __shared__ float red1[8][2][16], red2[8][2][16];

    for (int tile = blockIdx.x; tile < ntiles; tile += gridDim.x) {
        int row0 = tile * 32;

        // ---- A fragments for 2 row-tiles ----
        bf16x8 Aa[2][4], Ax[2][4];
#pragma unroll
        for (int Mt = 0; Mt < 2; ++Mt) {
            int mrow = row0 + Mt * 16 + lc;
            if (mrow >= n) mrow = n - 1;
            const unsigned short* pa = agg_bf + (size_t)mrow * IN_C + g * 8;
            const unsigned short* px = x_bf   + (size_t)mrow * IN_C + g * 8;
#pragma unroll
            for (int kt = 0; kt < 4; ++kt) {
                Aa[Mt][kt] = *reinterpret_cast<const bf16x8*>(pa + kt * 32);
                Ax[Mt][kt] = *reinterpret_cast<const bf16x8*>(px + kt * 32);
            }
        }

        f32x4 accg[2][2], accr[2][2];   // [Mt][ct2]
#pragma unroll
        for (int Mt = 0; Mt < 2; ++Mt)
#pragma unroll
            for (int ct2 = 0; ct2 < 2; ++ct2) {
                accg[Mt][ct2] = (f32x4){0.f, 0.f, 0.f, 0.f};
                accr[Mt][ct2] = (f32x4){0.f, 0.f, 0.f, 0.f};
            }

#pragma unroll
        for (int kt = 0; kt < 4; ++kt)
#pragma unroll
            for (int ct2 = 0; ct2 < 2; ++ct2)
#pragma unroll
                for (int Mt = 0; Mt < 2; ++Mt) {
                    accg[Mt][ct2] = __builtin_amdgcn_mfma_f32_16x16x32_bf16(Aa[Mt][kt], Bg[ct2][kt], accg[Mt][ct2], 0, 0, 0);
                    accr[Mt][ct2] = __builtin_amdgcn_mfma_f32_16x16x32_bf16(Ax[Mt][kt], Br[ct2][kt], accr[Mt][ct2], 0, 0, 0);
                }

        // ---- LayerNorm partials: sum over this wave's 32 cols ----
        float s1[2][4], s2[2][4];
#pragma unroll
        for (int Mt = 0; Mt < 2; ++Mt)
#pragma unroll
            for (int r = 0; r < 4; ++r) {
                float a = 0.f, b = 0.f;
#pragma unroll
                for (int ct2 = 0; ct2 < 2; ++ct2) {
                    float v = accg[Mt][ct2][r] + bgj[ct2];
                    accg[Mt][ct2][r] = v;
                    a += v; b += v * v;
                }
                s1[Mt][r] = a; s2[Mt][r] = b;
            }
#pragma unroll
        for (int off = 1; off < 16; off <<= 1)
#pragma unroll
            for (int Mt = 0; Mt < 2; ++Mt)
#pragma unroll
                for (int r = 0; r < 4; ++r) {
                    s1[Mt][r] += __shfl_xor(s1[Mt][r], off);
                    s2[Mt][r] += __shfl_xor(s2[Mt][r], off);
                }
        if (lc == 0) {
#pragma unroll
            for (int Mt = 0; Mt < 2; ++Mt)
#pragma unroll
                for (int r = 0; r < 4; ++r) {
                    red1[w][Mt][g * 4 + r] = s1[Mt][r];
                    red2[w][Mt][g * 4 + r] = s2[Mt][r];
                }
        }
        __syncthreads();

        float mu[2][4], rs[2][4];
#pragma unroll
        for (int Mt = 0; Mt < 2; ++Mt)
#pragma unroll
            for (int r = 0; r < 4; ++r) {
                float t1 = 0.f, t2 = 0.f;
#pragma unroll
                for (int wv = 0; wv < 8; ++wv) {
                    t1 += red1[wv][Mt][g * 4 + r];
                    t2 += red2[wv][Mt][g * 4 + r];
                }
                float m = t1 * (1.f / OUT_C);
                float var = t2 * (1.f / OUT_C) - m * m;
                mu[Mt][r] = m;
                rs[Mt][r] = rsqrtf(var + LN_EPS);
            }

        // ---- epilogue + store ----
#pragma unroll
        for (int Mt = 0; Mt < 2; ++Mt)
#pragma unroll
            for (int r = 0; r < 4; ++r) {
                int rown = row0 + Mt * 16 + g * 4 + r;
                if (rown < n) {
#pragma unroll
                    for (int ct2 = 0; ct2 < 2; ++ct2) {
                        float ln = (accg[Mt][ct2][r] - mu[Mt][r]) * rs[Mt][r] * gj[ct2] + bj[ct2];
                        float val = fmaxf(ln, 0.f) + accr[Mt][ct2][r] + brj[ct2];
                        out[(size_t)rown * OUT_C + colj[ct2]] = val;
                    }
                }
            }
        __syncthreads();   // red reuse next tile
    }
}

extern "C" void kernel_launch(void* const* d_in, const int* in_sizes, int n_in,
                              void* d_out, int out_size, void* d_ws, size_t ws_size,
                              hipStream_t stream) {
    const float* x     = (const float*)d_in[0];
    const int*   ei    = (const int*)d_in[1];
    const float* Wg    = (const float*)d_in[2];
    const float* bg    = (const float*)d_in[3];
    const float* gamma = (const float*)d_in[4];
    const float* beta  = (const float*)d_in[5];
    const float* Wr    = (const float*)d_in[6];
    const float* br    = (const float*)d_in[7];
    float* out = (float*)d_out;

    int N = in_sizes[0] / IN_C;
    int E = in_sizes[1] / 2;
    const int* row = ei;
    const int* col = ei + E;

    char* ws = (char*)d_ws;
    size_t off = 0;
    auto alloc = [&](size_t bytes) -> void* {
        void* p = ws + off;
        off += (bytes + 255) & ~(size_t)255;
        return p;
    };
    unsigned short* x_bf   = (unsigned short*)alloc((size_t)N * IN_C * 2);
    unsigned short* xs_bf  = (unsigned short*)alloc((size_t)N * IN_C * 2);
    unsigned short* agg_bf = (unsigned short*)alloc((size_t)N * IN_C * 2);
    unsigned short* wgf    = (unsigned short*)alloc((size_t)IN_C * OUT_C * 2);
    unsigned short* wrf    = (unsigned short*)alloc((size_t)IN_C * OUT_C * 2);
    float* dinv    = (float*)alloc((size_t)N * sizeof(float));
    int*   cursor  = (int*)alloc((size_t)N * sizeof(int));   // becomes deg
    int*   ptr     = (int*)alloc((size_t)(N + 1) * sizeof(int));
    int*   bsum    = (int*)alloc(64 * sizeof(int));
    unsigned short* slot = (unsigned short*)alloc((size_t)E * sizeof(unsigned short));
    int*   csr_row = (int*)alloc((size_t)E * sizeof(int));
    (void)ws_size; (void)n_in; (void)out_size;

    int nbN  = (N + 255) / 256;
    int nbE2 = (E + 511) / 512;
    int nsb  = (N + SCAN_BLK - 1) / SCAN_BLK;
    int ncvt = (N * (IN_C / 8) + 255) / 256;
    int ntiles = (N + 31) / 32;
    int ngemm = ntiles < 256 ? ntiles : 256;

    hipMemsetAsync(cursor, 0, (size_t)N * sizeof(int), stream);
    k_slot   <<<nbE2, 256, 0, stream>>>(col, cursor, slot, E);
    k_scan1  <<<nsb, 1024, 0, stream>>>(cursor, ptr, bsum, dinv, N);
    k_scan2  <<<1, 64, 0, stream>>>(bsum, nsb);
    k_scan3  <<<nbN, 256, 0, stream>>>(ptr, bsum, N, E);
    k_place  <<<nbE2, 256, 0, stream>>>(row, col, ptr, slot, csr_row, E);
    k_convert<<<ncvt, 256, 0, stream>>>(x, dinv, Wg, Wr, x_bf, xs_bf, wgf, wrf, N);
    k_agg    <<<(N + 3) / 4, 256, 0, stream>>>((const unsigned int*)xs_bf, dinv, ptr, csr_row, agg_bf, N);
    k_mfma   <<<ngemm, 512, 0, stream>>>(agg_bf, x_bf, wgf, wrf, bg, gamma, beta, br, out, N, ntiles);
}

// Round 6
// 145.522 us; speedup vs baseline: 1.1320x; 1.1320x over previous
//
#include <hip/hip_runtime.h>

#define IN_C 128
#define OUT_C 256
#define LN_EPS 1e-5f
#define SCAN_BLK 1024

typedef __attribute__((ext_vector_type(8))) short bf16x8;
typedef __attribute__((ext_vector_type(4))) float f32x4;

__device__ __forceinline__ unsigned int f2bf(float f) {
    unsigned int u = __float_as_uint(f);
    return (u + 0x7fffu + ((u >> 16) & 1u)) >> 16;   // RNE
}
__device__ __forceinline__ float bf_lo(unsigned int p) { return __uint_as_float(p << 16); }
__device__ __forceinline__ float bf_hi(unsigned int p) { return __uint_as_float(p & 0xffff0000u); }

// ---------- pass 1: per-edge slot reservation (the ONLY atomic pass) ----------
__global__ __launch_bounds__(256) void k_slot(const int* __restrict__ col,
                                              int* __restrict__ cursor,
                                              unsigned short* __restrict__ slot, int E) {
    int i = blockIdx.x * 256 + threadIdx.x;
    int base = i * 2;
    if (base + 1 < E) {
        int2 c = *reinterpret_cast<const int2*>(col + base);
        unsigned short s0 = (unsigned short)atomicAdd(&cursor[c.x], 1);
        unsigned short s1 = (unsigned short)atomicAdd(&cursor[c.y], 1);
        ushort2 sv; sv.x = s0; sv.y = s1;
        *reinterpret_cast<ushort2*>(slot + base) = sv;
    } else if (base < E) {
        slot[base] = (unsigned short)atomicAdd(&cursor[col[base]], 1);
    }
}

// ---------- scan of deg (=cursor) -> exclusive ptr, plus dinv = rsqrt(deg+1) ----------
__global__ __launch_bounds__(1024) void k_scan1(const int* __restrict__ deg, int* __restrict__ ptr,
                                                int* __restrict__ bsum, float* __restrict__ dinv, int n) {
    __shared__ int s[SCAN_BLK];
    int t = threadIdx.x;
    int i = blockIdx.x * SCAN_BLK + t;
    int v = (i < n) ? deg[i] : 0;
    s[t] = v;
    __syncthreads();
    for (int off = 1; off < SCAN_BLK; off <<= 1) {
        int add = (t >= off) ? s[t - off] : 0;
        __syncthreads();
        s[t] += add;
        __syncthreads();
    }
    if (i < n) { ptr[i] = s[t] - v; dinv[i] = rsqrtf((float)(v + 1)); }
    if (t == SCAN_BLK - 1) bsum[blockIdx.x] = s[t];
}

__global__ __launch_bounds__(64) void k_scan2(int* __restrict__ bsum, int nb) {
    __shared__ int s[64];
    int t = threadIdx.x;
    int v = (t < nb) ? bsum[t] : 0;
    s[t] = v;
    __syncthreads();
    for (int off = 1; off < 64; off <<= 1) {
        int add = (t >= off) ? s[t - off] : 0;
        __syncthreads();
        s[t] += add;
        __syncthreads();
    }
    if (t < nb) bsum[t] = s[t] - v;
}

__global__ __launch_bounds__(256) void k_scan3(int* __restrict__ ptr, const int* __restrict__ bsum,
                                               int n, int E) {
    int i = blockIdx.x * 256 + threadIdx.x;
    if (i < n) ptr[i] += bsum[i / SCAN_BLK];
    if (i == 0) ptr[n] = E;
}

// ---------- pass 2: atomic-free CSR placement ----------
__global__ __launch_bounds__(256) void k_place(const int* __restrict__ row, const int* __restrict__ col,
                                               const int* __restrict__ ptr,
                                               const unsigned short* __restrict__ slot,
                                               int* __restrict__ csr_row, int E) {
    int i = blockIdx.x * 256 + threadIdx.x;
    int base = i * 2;
    if (base + 1 < E) {
        int2 r = *reinterpret_cast<const int2*>(row + base);
        int2 c = *reinterpret_cast<const int2*>(col + base);
        ushort2 s = *reinterpret_cast<const ushort2*>(slot + base);
        csr_row[ptr[c.x] + s.x] = r.x;
        csr_row[ptr[c.y] + s.y] = r.y;
    } else if (base < E) {
        csr_row[ptr[col[base]] + slot[base]] = row[base];
    }
}

// ---------- conversions: x->bf16 (plain and dinv-scaled), weights->fragment order ----------
__global__ __launch_bounds__(256) void k_convert(const float* __restrict__ x,
                                                 const float* __restrict__ dinv,
                                                 const float* __restrict__ Wg,
                                                 const float* __restrict__ Wr,
                                                 unsigned short* __restrict__ x_bf,
                                                 unsigned short* __restrict__ xs_bf,
                                                 unsigned short* __restrict__ wgf,
                                                 unsigned short* __restrict__ wrf,
                                                 int n) {
    int gid = blockIdx.x * 256 + threadIdx.x;
    int nx8 = n * (IN_C / 8);
    if (gid < nx8) {
        float dn = dinv[gid >> 4];
        const float4* xv = reinterpret_cast<const float4*>(x) + (size_t)gid * 2;
        float4 a = xv[0], b = xv[1];
        uint4 o, os;
        o.x  = f2bf(a.x) | (f2bf(a.y) << 16);
        o.y  = f2bf(a.z) | (f2bf(a.w) << 16);
        o.z  = f2bf(b.x) | (f2bf(b.y) << 16);
        o.w  = f2bf(b.z) | (f2bf(b.w) << 16);
        os.x = f2bf(a.x * dn) | (f2bf(a.y * dn) << 16);
        os.y = f2bf(a.z * dn) | (f2bf(a.w * dn) << 16);
        os.z = f2bf(b.x * dn) | (f2bf(b.y * dn) << 16);
        os.w = f2bf(b.z * dn) | (f2bf(b.w * dn) << 16);
        reinterpret_cast<uint4*>(x_bf)[gid]  = o;
        reinterpret_cast<uint4*>(xs_bf)[gid] = os;
    }
    if (gid < 8192) {  // weight fragments
        int wsel = gid >> 12;
        int u = gid & 4095;
        int ct = u >> 8, kt = (u >> 6) & 3, l = u & 63;
        int k0 = kt * 32 + (l >> 4) * 8;
        int colw = ct * 16 + (l & 15);
        const float* W = wsel ? Wr : Wg;
        unsigned short* Wf = wsel ? wrf : wgf;
        uint4 o;
        unsigned int s[8];
#pragma unroll
        for (int e = 0; e < 8; ++e) s[e] = f2bf(W[(size_t)(k0 + e) * OUT_C + colw]);
        o.x = s[0] | (s[1] << 16); o.y = s[2] | (s[3] << 16);
        o.z = s[4] | (s[5] << 16); o.w = s[6] | (s[7] << 16);
        reinterpret_cast<uint4*>(Wf)[u] = o;
    }
}

// ---------- aggregation: agg[c] = dinv[c] * (xs[c] + sum_e xs[r]), unroll x8 ----------
__global__ __launch_bounds__(256) void k_agg(const unsigned int* __restrict__ xs32,
                                             const float* __restrict__ dinv,
                                             const int* __restrict__ ptr,
                                             const int* __restrict__ csr_row,
                                             unsigned short* __restrict__ agg_bf, int n) {
    int c = blockIdx.x * 4 + (threadIdx.x >> 6);
    if (c >= n) return;
    int lane = threadIdx.x & 63;
    float dc = dinv[c];
    unsigned int p = xs32[(size_t)c * 64 + lane];
    float a0 = bf_lo(p), a1 = bf_hi(p);
    int e = ptr[c], end = ptr[c + 1];
    for (; e + 8 <= end; e += 8) {
        int r0 = csr_row[e],     r1 = csr_row[e + 1], r2 = csr_row[e + 2], r3 = csr_row[e + 3];
        int r4 = csr_row[e + 4], r5 = csr_row[e + 5], r6 = csr_row[e + 6], r7 = csr_row[e + 7];
        unsigned int q0 = xs32[(size_t)r0 * 64 + lane];
        unsigned int q1 = xs32[(size_t)r1 * 64 + lane];
        unsigned int q2 = xs32[(size_t)r2 * 64 + lane];
        unsigned int q3 = xs32[(size_t)r3 * 64 + lane];
        unsigned int q4 = xs32[(size_t)r4 * 64 + lane];
        unsigned int q5 = xs32[(size_t)r5 * 64 + lane];
        unsigned int q6 = xs32[(size_t)r6 * 64 + lane];
        unsigned int q7 = xs32[(size_t)r7 * 64 + lane];
        a0 += bf_lo(q0); a1 += bf_hi(q0);
        a0 += bf_lo(q1); a1 += bf_hi(q1);
        a0 += bf_lo(q2); a1 += bf_hi(q2);
        a0 += bf_lo(q3); a1 += bf_hi(q3);
        a0 += bf_lo(q4); a1 += bf_hi(q4);
        a0 += bf_lo(q5); a1 += bf_hi(q5);
        a0 += bf_lo(q6); a1 += bf_hi(q6);
        a0 += bf_lo(q7); a1 += bf_hi(q7);
    }
    for (; e < end; ++e) {
        unsigned int q = xs32[(size_t)csr_row[e] * 64 + lane];
        a0 += bf_lo(q); a1 += bf_hi(q);
    }
    a0 *= dc; a1 *= dc;
    *reinterpret_cast<unsigned int*>(agg_bf + (size_t)c * IN_C + lane * 2) = f2bf(a0) | (f2bf(a1) << 16);
}

// ---------- fused MFMA dual-GEMM (transposed output) + LN + ReLU + residual ----------
// 8 waves; wave w owns cols [w*32, w*32+32). W register-resident as A-operand;
// X fragments are B-operand, prefetched 1 tile ahead. 16-row tiles, 1 barrier/tile,
// double-buffered LDS reduction, dwordx4 stores (lane owns 4 consecutive cols of 1 row).
__global__ __launch_bounds__(512, 2) void k_mfma(const unsigned short* __restrict__ agg_bf,
                                                 const unsigned short* __restrict__ x_bf,
                                                 const unsigned short* __restrict__ wgf,
                                                 const unsigned short* __restrict__ wrf,
                                                 const float* __restrict__ bgc,
                                                 const float* __restrict__ gamma,
                                                 const float* __restrict__ beta,
                                                 const float* __restrict__ brc,
                                                 float* __restrict__ out, int n, int ntiles, int chunk) {
    int tid = threadIdx.x;
    int w = tid >> 6, l = tid & 63;
    int g = l >> 4, lc = l & 15;

    int t0 = blockIdx.x * chunk;
    int tend = t0 + chunk;
    if (tend > ntiles) tend = ntiles;
    if (t0 >= tend) return;

    // ---- resident W fragments (used as MFMA A-operand) ----
    bf16x8 Wgf[2][4], Wrf[2][4];
#pragma unroll
    for (int ct2 = 0; ct2 < 2; ++ct2)
#pragma unroll
        for (int kt = 0; kt < 4; ++kt) {
            size_t idx = ((size_t)((w * 2 + ct2) * 4 + kt) * 64 + l) * 8;
            Wgf[ct2][kt] = *reinterpret_cast<const bf16x8*>(wgf + idx);
            Wrf[ct2][kt] = *reinterpret_cast<const bf16x8*>(wrf + idx);
        }

    // ---- per-lane epilogue params: 4 consecutive cols at (w*2+ct2)*16 + g*4 ----
    float4 Pbg[2], Pga[2], Pbe[2], Pbr[2];
#pragma unroll
    for (int ct2 = 0; ct2 < 2; ++ct2) {
        int c0 = (w * 2 + ct2) * 16 + g * 4;
        Pbg[ct2] = *reinterpret_cast<const float4*>(bgc + c0);
        Pga[ct2] = *reinterpret_cast<const float4*>(gamma + c0);
        Pbe[ct2] = *reinterpret_cast<const float4*>(beta + c0);
        Pbr[ct2] = *reinterpret_cast<const float4*>(brc + c0);
    }

    __shared__ float red1[2][8][16], red2[2][8][16];

    // ---- prologue: load X fragments (B-operand) for first tile ----
    bf16x8 Fa[4], Fx[4];
    {
        int mrow = t0 * 16 + lc;
        if (mrow >= n) mrow = n - 1;
        const unsigned short* pa = agg_bf + (size_t)mrow * IN_C + g * 8;
        const unsigned short* px = x_bf   + (size_t)mrow * IN_C + g * 8;
#pragma unroll
        for (int kt = 0; kt < 4; ++kt) {
            Fa[kt] = *reinterpret_cast<const bf16x8*>(pa + kt * 32);
            Fx[kt] = *reinterpret_cast<const bf16x8*>(px + kt * 32);
        }
    }

    for (int t = t0; t < tend; ++t) {
        f32x4 Ag[2], Ar[2];
#pragma unroll
        for (int ct2 = 0; ct2 < 2; ++ct2) {
            Ag[ct2] = (f32x4){0.f, 0.f, 0.f, 0.f};
            Ar[ct2] = (f32x4){0.f, 0.f, 0.f, 0.f};
        }

        // ---- MFMAs: D^T = W^T-as-A x X-as-B. Lane: row = lc, cols = base+g*4+r ----
#pragma unroll
        for (int kt = 0; kt < 4; ++kt)
#pragma unroll
            for (int ct2 = 0; ct2 < 2; ++ct2) {
                Ag[ct2] = __builtin_amdgcn_mfma_f32_16x16x32_bf16(Wgf[ct2][kt], Fa[kt], Ag[ct2], 0, 0, 0);
                Ar[ct2] = __builtin_amdgcn_mfma_f32_16x16x32_bf16(Wrf[ct2][kt], Fx[kt], Ar[ct2], 0, 0, 0);
            }

        // ---- prefetch next tile's X fragments (hidden under LN + store + barrier) ----
        {
            int tn = (t + 1 < tend) ? t + 1 : t;
            int mrow = tn * 16 + lc;
            if (mrow >= n) mrow = n - 1;
            const unsigned short* pa = agg_bf + (size_t)mrow * IN_C + g * 8;
            const unsigned short* px = x_bf   + (size_t)mrow * IN_C + g * 8;
#pragma unroll
            for (int kt = 0; kt < 4; ++kt) {
                Fa[kt] = *reinterpret_cast<const bf16x8*>(pa + kt * 32);
                Fx[kt] = *reinterpret_cast<const bf16x8*>(px + kt * 32);
            }
        }

        // ---- LN partials: lane sums its 8 cols of row lc, then reduce over g-groups ----
        float s1 = 0.f, s2 = 0.f;
#pragma unroll
        for (int ct2 = 0; ct2 < 2; ++ct2) {
            const float* pb = reinterpret_cast<const float*>(&Pbg[ct2]);
#pragma unroll
            for (int r = 0; r < 4; ++r) {
                float v = Ag[ct2][r] + pb[r];
                Ag[ct2][r] = v;
                s1 += v; s2 += v * v;
            }
        }
        s1 += __shfl_xor(s1, 16); s2 += __shfl_xor(s2, 16);
        s1 += __shfl_xor(s1, 32); s2 += __shfl_xor(s2, 32);

        int buf = t & 1;
        if (l < 16) { red1[buf][w][lc] = s1; red2[buf][w][lc] = s2; }
        __syncthreads();

        float u1 = 0.f, u2 = 0.f;
#pragma unroll
        for (int wv = 0; wv < 8; ++wv) {
            u1 += red1[buf][wv][lc];
            u2 += red2[buf][wv][lc];
        }
        float mu  = u1 * (1.f / OUT_C);
        float var = u2 * (1.f / OUT_C) - mu * mu;
        float rs  = rsqrtf(var + LN_EPS);

        // ---- epilogue: dwordx4 store of 4 consecutive cols of row lc ----
        int rown = t * 16 + lc;
        if (rown < n) {
#pragma unroll
            for (int ct2 = 0; ct2 < 2; ++ct2) {
                const float* pg = reinterpret_cast<const float*>(&Pga[ct2]);
                const float* pe = reinterpret_cast<const float*>(&Pbe[ct2]);
                const float* pr = reinterpret_cast<const float*>(&Pbr[ct2]);
                f32x4 o;
#pragma unroll
                for (int r = 0; r < 4; ++r) {
                    float ln = (Ag[ct2][r] - mu) * rs * pg[r] + pe[r];
                    o[r] = fmaxf(ln, 0.f) + Ar[ct2][r] + pr[r];
                }
                *reinterpret_cast<f32x4*>(out + (size_t)rown * OUT_C + (w * 2 + ct2) * 16 + g * 4) = o;
            }
        }
    }
}

extern "C" void kernel_launch(void* const* d_in, const int* in_sizes, int n_in,
                              void* d_out, int out_size, void* d_ws, size_t ws_size,
                              hipStream_t stream) {
    const float* x     = (const float*)d_in[0];
    const int*   ei    = (const int*)d_in[1];
    const float* Wg    = (const float*)d_in[2];
    const float* bg    = (const float*)d_in[3];
    const float* gamma = (const float*)d_in[4];
    const float* beta  = (const float*)d_in[5];
    const float* Wr    = (const float*)d_in[6];
    const float* br    = (const float*)d_in[7];
    float* out = (float*)d_out;

    int N = in_sizes[0] / IN_C;
    int E = in_sizes[1] / 2;
    const int* row = ei;
    const int* col = ei + E;

    char* ws = (char*)d_ws;
    size_t off = 0;
    auto alloc = [&](size_t bytes) -> void* {
        void* p = ws + off;
        off += (bytes + 255) & ~(size_t)255;
        return p;
    };
    unsigned short* x_bf   = (unsigned short*)alloc((size_t)N * IN_C * 2);
    unsigned short* xs_bf  = (unsigned short*)alloc((size_t)N * IN_C * 2);
    unsigned short* agg_bf = (unsigned short*)alloc((size_t)N * IN_C * 2);
    unsigned short* wgf    = (unsigned short*)alloc((size_t)IN_C * OUT_C * 2);
    unsigned short* wrf    = (unsigned short*)alloc((size_t)IN_C * OUT_C * 2);
    float* dinv    = (float*)alloc((size_t)N * sizeof(float));
    int*   cursor  = (int*)alloc((size_t)N * sizeof(int));   // becomes deg
    int*   ptr     = (int*)alloc((size_t)(N + 1) * sizeof(int));
    int*   bsum    = (int*)alloc(64 * sizeof(int));
    unsigned short* slot = (unsigned short*)alloc((size_t)E * sizeof(unsigned short));
    int*   csr_row = (int*)alloc((size_t)E * sizeof(int));
    (void)ws_size; (void)n_in; (void)out_size;

    int nbN  = (N + 255) / 256;
    int nbE2 = (E + 511) / 512;
    int nsb  = (N + SCAN_BLK - 1) / SCAN_BLK;
    int ncvt = (N * (IN_C / 8) + 255) / 256;
    int ntiles = (N + 15) / 16;
    int ngrid  = 256;
    int chunk  = (ntiles + ngrid - 1) / ngrid;

    hipMemsetAsync(cursor, 0, (size_t)N * sizeof(int), stream);
    k_slot   <<<nbE2, 256, 0, stream>>>(col, cursor, slot, E);
    k_scan1  <<<nsb, 1024, 0, stream>>>(cursor, ptr, bsum, dinv, N);
    k_scan2  <<<1, 64, 0, stream>>>(bsum, nsb);
    k_scan3  <<<nbN, 256, 0, stream>>>(ptr, bsum, N, E);
    k_place  <<<nbE2, 256, 0, stream>>>(row, col, ptr, slot, csr_row, E);
    k_convert<<<ncvt, 256, 0, stream>>>(x, dinv, Wg, Wr, x_bf, xs_bf, wgf, wrf, N);
    k_agg    <<<(N + 3) / 4, 256, 0, stream>>>((const unsigned int*)xs_bf, dinv, ptr, csr_row, agg_bf, N);
    k_mfma   <<<ngrid, 512, 0, stream>>>(agg_bf, x_bf, wgf, wrf, bg, gamma, beta, br, out, N, ntiles, chunk);
}

// Round 7
// 145.264 us; speedup vs baseline: 1.1340x; 1.0018x over previous
//
#include <hip/hip_runtime.h>

#define IN_C 128
#define OUT_C 256
#define LN_EPS 1e-5f
#define SCAN_BLK 1024

typedef __attribute__((ext_vector_type(8))) short bf16x8;
typedef __attribute__((ext_vector_type(4))) float f32x4;

__device__ __forceinline__ unsigned int f2bf(float f) {
    unsigned int u = __float_as_uint(f);
    return (u + 0x7fffu + ((u >> 16) & 1u)) >> 16;   // RNE
}
__device__ __forceinline__ float bf_lo(unsigned int p) { return __uint_as_float(p << 16); }
__device__ __forceinline__ float bf_hi(unsigned int p) { return __uint_as_float(p & 0xffff0000u); }

// ---------- zero cursor (replaces pathological rocclr fill) ----------
__global__ __launch_bounds__(256) void k_zero(int4* __restrict__ p, int n4) {
    int i = blockIdx.x * 256 + threadIdx.x;
    if (i < n4) p[i] = (int4){0, 0, 0, 0};
}

// ---------- pass 1: per-edge slot reservation (the ONLY atomic pass), 8 edges/thread ----------
__global__ __launch_bounds__(256) void k_slot(const int* __restrict__ col,
                                              int* __restrict__ cursor,
                                              unsigned short* __restrict__ slot, int E) {
    int i = blockIdx.x * 256 + threadIdx.x;
    int base = i * 8;
    if (base + 8 <= E) {
        int4 c0 = *reinterpret_cast<const int4*>(col + base);
        int4 c1 = *reinterpret_cast<const int4*>(col + base + 4);
        unsigned int s0 = (unsigned int)atomicAdd(&cursor[c0.x], 1);
        unsigned int s1 = (unsigned int)atomicAdd(&cursor[c0.y], 1);
        unsigned int s2 = (unsigned int)atomicAdd(&cursor[c0.z], 1);
        unsigned int s3 = (unsigned int)atomicAdd(&cursor[c0.w], 1);
        unsigned int s4 = (unsigned int)atomicAdd(&cursor[c1.x], 1);
        unsigned int s5 = (unsigned int)atomicAdd(&cursor[c1.y], 1);
        unsigned int s6 = (unsigned int)atomicAdd(&cursor[c1.z], 1);
        unsigned int s7 = (unsigned int)atomicAdd(&cursor[c1.w], 1);
        uint4 o;
        o.x = (s0 & 0xffffu) | (s1 << 16);
        o.y = (s2 & 0xffffu) | (s3 << 16);
        o.z = (s4 & 0xffffu) | (s5 << 16);
        o.w = (s6 & 0xffffu) | (s7 << 16);
        *reinterpret_cast<uint4*>(slot + base) = o;
    } else {
        for (int e = base; e < E; ++e)
            slot[e] = (unsigned short)atomicAdd(&cursor[col[e]], 1);
    }
}

// ---------- scan of deg (=cursor) -> exclusive ptr, plus dinv = rsqrt(deg+1) ----------
__global__ __launch_bounds__(1024) void k_scan1(const int* __restrict__ deg, int* __restrict__ ptr,
                                                int* __restrict__ bsum, float* __restrict__ dinv, int n) {
    __shared__ int s[SCAN_BLK];
    int t = threadIdx.x;
    int i = blockIdx.x * SCAN_BLK + t;
    int v = (i < n) ? deg[i] : 0;
    s[t] = v;
    __syncthreads();
    for (int off = 1; off < SCAN_BLK; off <<= 1) {
        int add = (t >= off) ? s[t - off] : 0;
        __syncthreads();
        s[t] += add;
        __syncthreads();
    }
    if (i < n) { ptr[i] = s[t] - v; dinv[i] = rsqrtf((float)(v + 1)); }
    if (t == SCAN_BLK - 1) bsum[blockIdx.x] = s[t];
}

__global__ __launch_bounds__(64) void k_scan2(int* __restrict__ bsum, int nb) {
    __shared__ int s[64];
    int t = threadIdx.x;
    int v = (t < nb) ? bsum[t] : 0;
    s[t] = v;
    __syncthreads();
    for (int off = 1; off < 64; off <<= 1) {
        int add = (t >= off) ? s[t - off] : 0;
        __syncthreads();
        s[t] += add;
        __syncthreads();
    }
    if (t < nb) bsum[t] = s[t] - v;
}

__global__ __launch_bounds__(256) void k_scan3(int* __restrict__ ptr, const int* __restrict__ bsum,
                                               int n, int E) {
    int i = blockIdx.x * 256 + threadIdx.x;
    if (i < n) ptr[i] += bsum[i / SCAN_BLK];
    if (i == 0) ptr[n] = E;
}

// ---------- pass 2: atomic-free CSR placement, 4 edges/thread ----------
__global__ __launch_bounds__(256) void k_place(const int* __restrict__ row, const int* __restrict__ col,
                                               const int* __restrict__ ptr,
                                               const unsigned short* __restrict__ slot,
                                               int* __restrict__ csr_row, int E) {
    int i = blockIdx.x * 256 + threadIdx.x;
    int base = i * 4;
    if (base + 4 <= E) {
        int4 r = *reinterpret_cast<const int4*>(row + base);
        int4 c = *reinterpret_cast<const int4*>(col + base);
        uint2 sp = *reinterpret_cast<const uint2*>(slot + base);
        int p0 = ptr[c.x], p1 = ptr[c.y], p2 = ptr[c.z], p3 = ptr[c.w];
        csr_row[p0 + (sp.x & 0xffffu)] = r.x;
        csr_row[p1 + (sp.x >> 16)]     = r.y;
        csr_row[p2 + (sp.y & 0xffffu)] = r.z;
        csr_row[p3 + (sp.y >> 16)]     = r.w;
    } else {
        for (int e = base; e < E; ++e)
            csr_row[ptr[col[e]] + slot[e]] = row[e];
    }
}

// ---------- conversions: x->bf16 (plain and dinv-scaled), weights->fragment order ----------
__global__ __launch_bounds__(256) void k_convert(const float* __restrict__ x,
                                                 const float* __restrict__ dinv,
                                                 const float* __restrict__ Wg,
                                                 const float* __restrict__ Wr,
                                                 unsigned short* __restrict__ x_bf,
                                                 unsigned short* __restrict__ xs_bf,
                                                 unsigned short* __restrict__ wgf,
                                                 unsigned short* __restrict__ wrf,
                                                 int n) {
    int gid = blockIdx.x * 256 + threadIdx.x;
    int nx8 = n * (IN_C / 8);
    if (gid < nx8) {
        float dn = dinv[gid >> 4];
        const float4* xv = reinterpret_cast<const float4*>(x) + (size_t)gid * 2;
        float4 a = xv[0], b = xv[1];
        uint4 o, os;
        o.x  = f2bf(a.x) | (f2bf(a.y) << 16);
        o.y  = f2bf(a.z) | (f2bf(a.w) << 16);
        o.z  = f2bf(b.x) | (f2bf(b.y) << 16);
        o.w  = f2bf(b.z) | (f2bf(b.w) << 16);
        os.x = f2bf(a.x * dn) | (f2bf(a.y * dn) << 16);
        os.y = f2bf(a.z * dn) | (f2bf(a.w * dn) << 16);
        os.z = f2bf(b.x * dn) | (f2bf(b.y * dn) << 16);
        os.w = f2bf(b.z * dn) | (f2bf(b.w * dn) << 16);
        reinterpret_cast<uint4*>(x_bf)[gid]  = o;
        reinterpret_cast<uint4*>(xs_bf)[gid] = os;
    }
    if (gid < 8192) {  // weight fragments
        int wsel = gid >> 12;
        int u = gid & 4095;
        int ct = u >> 8, kt = (u >> 6) & 3, l = u & 63;
        int k0 = kt * 32 + (l >> 4) * 8;
        int colw = ct * 16 + (l & 15);
        const float* W = wsel ? Wr : Wg;
        unsigned short* Wf = wsel ? wrf : wgf;
        uint4 o;
        unsigned int s[8];
#pragma unroll
        for (int e = 0; e < 8; ++e) s[e] = f2bf(W[(size_t)(k0 + e) * OUT_C + colw]);
        o.x = s[0] | (s[1] << 16); o.y = s[2] | (s[3] << 16);
        o.z = s[4] | (s[5] << 16); o.w = s[6] | (s[7] << 16);
        reinterpret_cast<uint4*>(Wf)[u] = o;
    }
}

// ---------- aggregation: agg[c] = dinv[c] * (xs[c] + sum_e xs[r]), unroll x8 ----------
__global__ __launch_bounds__(256) void k_agg(const unsigned int* __restrict__ xs32,
                                             const float* __restrict__ dinv,
                                             const int* __restrict__ ptr,
                                             const int* __restrict__ csr_row,
                                             unsigned short* __restrict__ agg_bf, int n) {
    int c = blockIdx.x * 4 + (threadIdx.x >> 6);
    if (c >= n) return;
    int lane = threadIdx.x & 63;
    float dc = dinv[c];
    unsigned int p = xs32[(size_t)c * 64 + lane];
    float a0 = bf_lo(p), a1 = bf_hi(p);
    int e = ptr[c], end = ptr[c + 1];
    for (; e + 8 <= end; e += 8) {
        int r0 = csr_row[e],     r1 = csr_row[e + 1], r2 = csr_row[e + 2], r3 = csr_row[e + 3];
        int r4 = csr_row[e + 4], r5 = csr_row[e + 5], r6 = csr_row[e + 6], r7 = csr_row[e + 7];
        unsigned int q0 = xs32[(size_t)r0 * 64 + lane];
        unsigned int q1 = xs32[(size_t)r1 * 64 + lane];
        unsigned int q2 = xs32[(size_t)r2 * 64 + lane];
        unsigned int q3 = xs32[(size_t)r3 * 64 + lane];
        unsigned int q4 = xs32[(size_t)r4 * 64 + lane];
        unsigned int q5 = xs32[(size_t)r5 * 64 + lane];
        unsigned int q6 = xs32[(size_t)r6 * 64 + lane];
        unsigned int q7 = xs32[(size_t)r7 * 64 + lane];
        a0 += bf_lo(q0); a1 += bf_hi(q0);
        a0 += bf_lo(q1); a1 += bf_hi(q1);
        a0 += bf_lo(q2); a1 += bf_hi(q2);
        a0 += bf_lo(q3); a1 += bf_hi(q3);
        a0 += bf_lo(q4); a1 += bf_hi(q4);
        a0 += bf_lo(q5); a1 += bf_hi(q5);
        a0 += bf_lo(q6); a1 += bf_hi(q6);
        a0 += bf_lo(q7); a1 += bf_hi(q7);
    }
    for (; e < end; ++e) {
        unsigned int q = xs32[(size_t)csr_row[e] * 64 + lane];
        a0 += bf_lo(q); a1 += bf_hi(q);
    }
    a0 *= dc; a1 *= dc;
    *reinterpret_cast<unsigned int*>(agg_bf + (size_t)c * IN_C + lane * 2) = f2bf(a0) | (f2bf(a1) << 16);
}

// ---------- fused MFMA dual-GEMM (transposed output) + LN + ReLU + residual ----------
__global__ __launch_bounds__(512, 2) void k_mfma(const unsigned short* __restrict__ agg_bf,
                                                 const unsigned short* __restrict__ x_bf,
                                                 const unsigned short* __restrict__ wgf,
                                                 const unsigned short* __restrict__ wrf,
                                                 const float* __restrict__ bgc,
                                                 const float* __restrict__ gamma,
                                                 const float* __restrict__ beta,
                                                 const float* __restrict__ brc,
                                                 float* __restrict__ out, int n, int ntiles, int chunk) {
    int tid = threadIdx.x;
    int w = tid >> 6, l = tid & 63;
    int g = l >> 4, lc = l & 15;

    int t0 = blockIdx.x * chunk;
    int tend = t0 + chunk;
    if (tend > ntiles) tend = ntiles;
    if (t0 >= tend) return;

    bf16x8 Wgf[2][4], Wrf[2][4];
#pragma unroll
    for (int ct2 = 0; ct2 < 2; ++ct2)
#pragma unroll
        for (int kt = 0; kt < 4; ++kt) {
            size_t idx = ((size_t)((w * 2 + ct2) * 4 + kt) * 64 + l) * 8;
            Wgf[ct2][kt] = *reinterpret_cast<const bf16x8*>(wgf + idx);
            Wrf[ct2][kt] = *reinterpret_cast<const bf16x8*>(wrf + idx);
        }

    float4 Pbg[2], Pga[2], Pbe[2], Pbr[2];
#pragma unroll
    for (int ct2 = 0; ct2 < 2; ++ct2) {
        int c0 = (w * 2 + ct2) * 16 + g * 4;
        Pbg[ct2] = *reinterpret_cast<const float4*>(bgc + c0);
        Pga[ct2] = *reinterpret_cast<const float4*>(gamma + c0);
        Pbe[ct2] = *reinterpret_cast<const float4*>(beta + c0);
        Pbr[ct2] = *reinterpret_cast<const float4*>(brc + c0);
    }

    __shared__ float red1[2][8][16], red2[2][8][16];

    bf16x8 Fa[4], Fx[4];
    {
        int mrow = t0 * 16 + lc;
        if (mrow >= n) mrow = n - 1;
        const unsigned short* pa = agg_bf + (size_t)mrow * IN_C + g * 8;
        const unsigned short* px = x_bf   + (size_t)mrow * IN_C + g * 8;
#pragma unroll
        for (int kt = 0; kt < 4; ++kt) {
            Fa[kt] = *reinterpret_cast<const bf16x8*>(pa + kt * 32);
            Fx[kt] = *reinterpret_cast<const bf16x8*>(px + kt * 32);
        }
    }

    for (int t = t0; t < tend; ++t) {
        f32x4 Ag[2], Ar[2];
#pragma unroll
        for (int ct2 = 0; ct2 < 2; ++ct2) {
            Ag[ct2] = (f32x4){0.f, 0.f, 0.f, 0.f};
            Ar[ct2] = (f32x4){0.f, 0.f, 0.f, 0.f};
        }

#pragma unroll
        for (int kt = 0; kt < 4; ++kt)
#pragma unroll
            for (int ct2 = 0; ct2 < 2; ++ct2) {
                Ag[ct2] = __builtin_amdgcn_mfma_f32_16x16x32_bf16(Wgf[ct2][kt], Fa[kt], Ag[ct2], 0, 0, 0);
                Ar[ct2] = __builtin_amdgcn_mfma_f32_16x16x32_bf16(Wrf[ct2][kt], Fx[kt], Ar[ct2], 0, 0, 0);
            }

        {
            int tn = (t + 1 < tend) ? t + 1 : t;
            int mrow = tn * 16 + lc;
            if (mrow >= n) mrow = n - 1;
            const unsigned short* pa = agg_bf + (size_t)mrow * IN_C + g * 8;
            const unsigned short* px = x_bf   + (size_t)mrow * IN_C + g * 8;
#pragma unroll
            for (int kt = 0; kt < 4; ++kt) {
                Fa[kt] = *reinterpret_cast<const bf16x8*>(pa + kt * 32);
                Fx[kt] = *reinterpret_cast<const bf16x8*>(px + kt * 32);
            }
        }

        float s1 = 0.f, s2 = 0.f;
#pragma unroll
        for (int ct2 = 0; ct2 < 2; ++ct2) {
            const float* pb = reinterpret_cast<const float*>(&Pbg[ct2]);
#pragma unroll
            for (int r = 0; r < 4; ++r) {
                float v = Ag[ct2][r] + pb[r];
                Ag[ct2][r] = v;
                s1 += v; s2 += v * v;
            }
        }
        s1 += __shfl_xor(s1, 16); s2 += __shfl_xor(s2, 16);
        s1 += __shfl_xor(s1, 32); s2 += __shfl_xor(s2, 32);

        int buf = t & 1;
        if (l < 16) { red1[buf][w][lc] = s1; red2[buf][w][lc] = s2; }
        __syncthreads();

        float u1 = 0.f, u2 = 0.f;
#pragma unroll
        for (int wv = 0; wv < 8; ++wv) {
            u1 += red1[buf][wv][lc];
            u2 += red2[buf][wv][lc];
        }
        float mu  = u1 * (1.f / OUT_C);
        float var = u2 * (1.f / OUT_C) - mu * mu;
        float rs  = rsqrtf(var + LN_EPS);

        int rown = t * 16 + lc;
        if (rown < n) {
#pragma unroll
            for (int ct2 = 0; ct2 < 2; ++ct2) {
                const float* pg = reinterpret_cast<const float*>(&Pga[ct2]);
                const float* pe = reinterpret_cast<const float*>(&Pbe[ct2]);
                const float* pr = reinterpret_cast<const float*>(&Pbr[ct2]);
                f32x4 o;
#pragma unroll
                for (int r = 0; r < 4; ++r) {
                    float ln = (Ag[ct2][r] - mu) * rs * pg[r] + pe[r];
                    o[r] = fmaxf(ln, 0.f) + Ar[ct2][r] + pr[r];
                }
                *reinterpret_cast<f32x4*>(out + (size_t)rown * OUT_C + (w * 2 + ct2) * 16 + g * 4) = o;
            }
        }
    }
}

extern "C" void kernel_launch(void* const* d_in, const int* in_sizes, int n_in,
                              void* d_out, int out_size, void* d_ws, size_t ws_size,
                              hipStream_t stream) {
    const float* x     = (const float*)d_in[0];
    const int*   ei    = (const int*)d_in[1];
    const float* Wg    = (const float*)d_in[2];
    const float* bg    = (const float*)d_in[3];
    const float* gamma = (const float*)d_in[4];
    const float* beta  = (const float*)d_in[5];
    const float* Wr    = (const float*)d_in[6];
    const float* br    = (const float*)d_in[7];
    float* out = (float*)d_out;

    int N = in_sizes[0] / IN_C;
    int E = in_sizes[1] / 2;
    const int* row = ei;
    const int* col = ei + E;

    char* ws = (char*)d_ws;
    size_t off = 0;
    auto alloc = [&](size_t bytes) -> void* {
        void* p = ws + off;
        off += (bytes + 255) & ~(size_t)255;
        return p;
    };
    unsigned short* x_bf   = (unsigned short*)alloc((size_t)N * IN_C * 2);
    unsigned short* xs_bf  = (unsigned short*)alloc((size_t)N * IN_C * 2);
    unsigned short* agg_bf = (unsigned short*)alloc((size_t)N * IN_C * 2);
    unsigned short* wgf    = (unsigned short*)alloc((size_t)IN_C * OUT_C * 2);
    unsigned short* wrf    = (unsigned short*)alloc((size_t)IN_C * OUT_C * 2);
    float* dinv    = (float*)alloc((size_t)N * sizeof(float));
    int*   cursor  = (int*)alloc((size_t)N * sizeof(int));   // becomes deg
    int*   ptr     = (int*)alloc((size_t)(N + 1) * sizeof(int));
    int*   bsum    = (int*)alloc(64 * sizeof(int));
    unsigned short* slot = (unsigned short*)alloc((size_t)E * sizeof(unsigned short));
    int*   csr_row = (int*)alloc((size_t)E * sizeof(int));
    (void)ws_size; (void)n_in; (void)out_size;

    int nbN  = (N + 255) / 256;
    int nbE8 = (E + 2047) / 2048;
    int nbE4 = (E + 1023) / 1024;
    int nsb  = (N + SCAN_BLK - 1) / SCAN_BLK;
    int ncvt = (N * (IN_C / 8) + 255) / 256;
    int ntiles = (N + 15) / 16;
    int ngrid  = 256;
    int chunk  = (ntiles + ngrid - 1) / ngrid;
    int n4     = (N + 3) / 4;   // cursor zeroing in int4 units (256B-aligned alloc, safe to round up)

    k_zero   <<<(n4 + 255) / 256, 256, 0, stream>>>((int4*)cursor, n4);
    k_slot   <<<nbE8, 256, 0, stream>>>(col, cursor, slot, E);
    k_scan1  <<<nsb, 1024, 0, stream>>>(cursor, ptr, bsum, dinv, N);
    k_scan2  <<<1, 64, 0, stream>>>(bsum, nsb);
    k_scan3  <<<nbN, 256, 0, stream>>>(ptr, bsum, N, E);
    k_place  <<<nbE4, 256, 0, stream>>>(row, col, ptr, slot, csr_row, E);
    k_convert<<<ncvt, 256, 0, stream>>>(x, dinv, Wg, Wr, x_bf, xs_bf, wgf, wrf, N);
    k_agg    <<<(N + 3) / 4, 256, 0, stream>>>((const unsigned int*)xs_bf, dinv, ptr, csr_row, agg_bf, N);
    k_mfma   <<<ngrid, 512, 0, stream>>>(agg_bf, x_bf, wgf, wrf, bg, gamma, beta, br, out, N, ntiles, chunk);
}